// Round 10
// baseline (295.875 us; speedup 1.0000x reference)
//
#include <hip/hip_runtime.h>
#include <math.h>
#include <stdint.h>

#define N_PTS 2048
#define I_DIM 16
#define H_DIM 64
#define O_DIM 64
#define NCUTS 8
#define NGROUPS 4
#define GN_EPS 1e-5f
#define GN_TOT 32768.0f   // 16 ch * 2048 pts per group

typedef __attribute__((ext_vector_type(8)))  short    short8;
typedef __attribute__((ext_vector_type(4)))  float    f32x4;
typedef __attribute__((ext_vector_type(16))) float    f32x16;
typedef __attribute__((ext_vector_type(4)))  uint32_t u32x4;

__device__ inline uint32_t cvt_pk_bf16(float lo, float hi) {
    uint32_t r;
    asm("v_cvt_pk_bf16_f32 %0, %1, %2" : "=v"(r) : "v"(lo), "v"(hi));
    return r;
}

__device__ inline short8 frag_of(uint32_t a, uint32_t b, uint32_t c, uint32_t d) {
    u32x4 t; t.x = a; t.y = b; t.z = c; t.w = d;
    return __builtin_bit_cast(short8, t);
}

__device__ inline float bf16hi_to_f(uint32_t w) {
    return __builtin_bit_cast(float, w & 0xFFFF0000u);
}
__device__ inline float bf16lo_to_f(uint32_t w) {
    return __builtin_bit_cast(float, w << 16);
}

// ---------------------------------------------------------------------------
// k_front: fused pack(points,nuv->pjp) + input MLP + GN1 per-block partials
// (NO atomics — partials reduced in k_apply1)
// ---------------------------------------------------------------------------
__global__ __launch_bounds__(256) void k_front(
    const float* __restrict__ points, const float* __restrict__ nuv,
    const float* __restrict__ features, const float* __restrict__ W1,
    const float* __restrict__ b1, const float* __restrict__ W2,
    const float* __restrict__ b2, float* __restrict__ out,
    float* __restrict__ pjp, float* __restrict__ part)
{
    __shared__ float f0s[4][H_DIM];
    __shared__ float sred[16], qred[16];
    const float SC = 0.70710678118654752f;
    int tid = threadIdx.x;
    int pl = tid >> 6, h = tid & 63;
    int n = blockIdx.x * 4 + pl;

    if (h < 3)            pjp[n * 8 + h] = points[n * 3 + h] * SC;
    else if (h == 3)      pjp[n * 8 + 3] = 0.f;
    else if (h < 7)       pjp[n * 8 + h] = nuv[n * 9 + (h - 4)];
    else if (h == 7)      pjp[n * 8 + 7] = 0.f;

    const float* fr = features + n * I_DIM;
    float s = b1[h];
    #pragma unroll
    for (int i = 0; i < I_DIM; ++i) s = fmaf(fr[i], W1[h * I_DIM + i], s);
    s = s > 0.f ? s : 0.2f * s;
    f0s[pl][h] = s;
    __syncthreads();
    float t = b2[h];
    #pragma unroll
    for (int k = 0; k < H_DIM; ++k) t = fmaf(f0s[pl][k], W2[h * H_DIM + k], t);
    t = t > 0.f ? t : 0.2f * t;
    out[n * H_DIM + h] = t;

    float ss = t, qq = t * t;
    #pragma unroll
    for (int off = 8; off >= 1; off >>= 1) {
        ss += __shfl_xor(ss, off);
        qq += __shfl_xor(qq, off);
    }
    int grp = pl * 4 + (h >> 4);
    if ((h & 15) == 0) { sred[grp] = ss; qred[grp] = qq; }
    __syncthreads();
    if (tid < 4) {
        float S = sred[tid] + sred[4 + tid] + sred[8 + tid] + sred[12 + tid];
        float Q = qred[tid] + qred[4 + tid] + qred[8 + tid] + qred[12 + tid];
        part[blockIdx.x * 8 + tid]     = S;
        part[blockIdx.x * 8 + 4 + tid] = Q;
    }
}

// ---------------------------------------------------------------------------
// k_apply1: reduce GN1 partials (512 blocks x 8) + normalize -> bf16 fbh
// 256 blocks x 256 thr; thread handles 2 consecutive elements.
// ---------------------------------------------------------------------------
__global__ __launch_bounds__(256) void k_apply1(
    const float* __restrict__ x, const float* __restrict__ part,
    const float* __restrict__ w, const float* __restrict__ b,
    uint32_t* __restrict__ fbh)
{
    __shared__ float s8[4][8];
    int tid = threadIdx.x;
    const f32x4* p4 = (const f32x4*)part;       // [512 blocks][S4|Q4]
    f32x4 sa = p4[tid * 4 + 0], qa = p4[tid * 4 + 1];
    f32x4 sb = p4[tid * 4 + 2], qb = p4[tid * 4 + 3];
    float sv0 = sa.x + sb.x, sv1 = sa.y + sb.y, sv2 = sa.z + sb.z, sv3 = sa.w + sb.w;
    float qv0 = qa.x + qb.x, qv1 = qa.y + qb.y, qv2 = qa.z + qb.z, qv3 = qa.w + qb.w;
    #pragma unroll
    for (int off = 1; off <= 32; off <<= 1) {
        sv0 += __shfl_xor(sv0, off); sv1 += __shfl_xor(sv1, off);
        sv2 += __shfl_xor(sv2, off); sv3 += __shfl_xor(sv3, off);
        qv0 += __shfl_xor(qv0, off); qv1 += __shfl_xor(qv1, off);
        qv2 += __shfl_xor(qv2, off); qv3 += __shfl_xor(qv3, off);
    }
    int lane = tid & 63, wvv = tid >> 6;
    if (lane == 0) {
        s8[wvv][0] = sv0; s8[wvv][1] = sv1; s8[wvv][2] = sv2; s8[wvv][3] = sv3;
        s8[wvv][4] = qv0; s8[wvv][5] = qv1; s8[wvv][6] = qv2; s8[wvv][7] = qv3;
    }
    __syncthreads();
    int idx2 = blockIdx.x * 256 + tid;
    int e = idx2 * 2;
    int ch = e & 63;
    int g = ch >> 4;
    float S = s8[0][g] + s8[1][g] + s8[2][g] + s8[3][g];
    float Q = s8[0][4 + g] + s8[1][4 + g] + s8[2][4 + g] + s8[3][4 + g];
    float m = S / GN_TOT;
    float var = Q / GN_TOT - m * m;
    float r = rsqrtf(var + GN_EPS);
    float v0 = (x[e]     - m) * r * w[ch]     + b[ch];
    float v1 = (x[e + 1] - m) * r * w[ch + 1] + b[ch + 1];
    fbh[idx2] = cvt_pk_bf16(v0, v1);
}

// ---------------------------------------------------------------------------
// k_conv: pairwise windowed conv via 32x32x16 MFMA.
// Block = point i, 4 independent waves; wave wv owns 64-j tiles jt=wv,wv+4,..
// K-slot split (lanes 0-31: k=0..7, lanes 32-63: k=8..15):
//   A[ch,0..7]=w2[ch][:], A[ch,8]=b2[ch]; B[0..7,j]=win*h[j][:], B[8,j]=win.
// Each lane computes the preamble for j = jt*64+lane (1x work); the two
// 32-col B-frags are built via 5 shfl_xor(.,32). Probed D layout (cc/jj)
// with m74/m101 quad-contiguity for vectorized f-loads AND red-writes
// (load/store consistent). out[i,ch] = sum_j relu(D[ch,j]) * f[j][ch].
// ---------------------------------------------------------------------------
__global__ __launch_bounds__(256, 4) void k_conv_mfma(
    const float* __restrict__ pjp, const float* __restrict__ nuv,
    const float* __restrict__ cw1, const float* __restrict__ cb1,
    const float* __restrict__ cw2, const float* __restrict__ cb2,
    const uint32_t* __restrict__ fbh, float* __restrict__ out)
{
    __shared__ float red[4][H_DIM];
    int i   = blockIdx.x;
    int tid = threadIdx.x;
    int lane = tid & 63, wv = tid >> 6;
    int l31 = lane & 31, lg2 = lane >> 5;

    const f32x16 z16 = {0.f,0.f,0.f,0.f,0.f,0.f,0.f,0.f,
                        0.f,0.f,0.f,0.f,0.f,0.f,0.f,0.f};

    // ---- layout probes (self-calibrating, 32x32 shape) -----------------
    uint32_t one_b = cvt_pk_bf16(1.f, 0.f);
    uint32_t idx_b = cvt_pk_bf16((float)l31, 0.f);
    short8 pIdx = frag_of(lg2 == 0 ? idx_b : 0u, 0u, 0u, 0u);
    short8 pOne = frag_of(lg2 == 0 ? one_b : 0u, 0u, 0u, 0u);
    f32x16 Dc = __builtin_amdgcn_mfma_f32_32x32x16_bf16(pIdx, pOne, z16, 0, 0, 0);
    f32x16 Dj = __builtin_amdgcn_mfma_f32_32x32x16_bf16(pOne, pIdx, z16, 0, 0, 0);
    int ccq[4];
    #pragma unroll
    for (int q = 0; q < 4; ++q) ccq[q] = ((int)(Dc[4 * q] + 0.5f)) >> 2;
    int jj0 = (int)(Dj[0] + 0.5f);

    // ---- per-block (uniform) point-i data ------------------------------
    float pix = pjp[i * 8 + 0];
    float piy = pjp[i * 8 + 1];
    float piz = pjp[i * 8 + 2];
    float nv[9];
    #pragma unroll
    for (int a = 0; a < 9; ++a) nv[a] = nuv[i * 9 + a];
    float w1c[NCUTS][3], bb1[NCUTS];
    #pragma unroll
    for (int c = 0; c < NCUTS; ++c) {
        w1c[c][0] = cw1[c * 3 + 0];
        w1c[c][1] = cw1[c * 3 + 1];
        w1c[c][2] = cw1[c * 3 + 2];
        bb1[c]    = cb1[c];
    }

    // ---- constant A-frags: m-tile covers ch = m*32 + (0..31) -----------
    short8 Af[2];
    #pragma unroll
    for (int m = 0; m < 2; ++m) {
        int ch = m * 32 + l31;
        uint32_t a0 = 0, a1 = 0, a2 = 0, a3 = 0;
        if (lg2 == 0) {
            a0 = cvt_pk_bf16(cw2[ch * 8 + 0], cw2[ch * 8 + 1]);
            a1 = cvt_pk_bf16(cw2[ch * 8 + 2], cw2[ch * 8 + 3]);
            a2 = cvt_pk_bf16(cw2[ch * 8 + 4], cw2[ch * 8 + 5]);
            a3 = cvt_pk_bf16(cw2[ch * 8 + 6], cw2[ch * 8 + 7]);
        } else {
            a0 = cvt_pk_bf16(cb2[ch], 0.f);   // k=8 slot: bias row
        }
        Af[m] = frag_of(a0, a1, a2, a3);
    }

    float acc[2][16];
    #pragma unroll
    for (int m = 0; m < 2; ++m)
        #pragma unroll
        for (int r = 0; r < 16; ++r) acc[m][r] = 0.f;

    const uint2* fh = (const uint2*)fbh;      // 16 uint2 per 64-ch row

    #pragma unroll 1
    for (int jt = wv; jt < N_PTS / 64; jt += 4) {
        // one preamble per lane, for its own j
        int j = jt * 64 + lane;
        f32x4 pa = ((const f32x4*)pjp)[j * 2 + 0];
        f32x4 pb = ((const f32x4*)pjp)[j * 2 + 1];
        float dx = pa.x - pix;
        float dy = pa.y - piy;
        float dz = pa.z - piz;
        float nd = nv[0] * pb.x + nv[1] * pb.y + nv[2] * pb.z;
        float tt = 2.f - nd;
        float d2 = (dx * dx + dy * dy + dz * dz) * tt * tt;
        float win = __expf(-d2);
        float P0 = nv[0] * dx + nv[1] * dy + nv[2] * dz;
        float P1 = nv[3] * dx + nv[4] * dy + nv[5] * dz;
        float P2 = nv[6] * dx + nv[7] * dy + nv[8] * dz;
        float hp[NCUTS];
        #pragma unroll
        for (int c = 0; c < NCUTS; ++c) {
            float v = fmaf(P0, w1c[c][0], fmaf(P1, w1c[c][1], fmaf(P2, w1c[c][2], bb1[c])));
            v = v > 0.f ? v : 0.f;
            hp[c] = win * v;                  // fold window into B
        }
        uint32_t hw0 = cvt_pk_bf16(hp[0], hp[1]);
        uint32_t hw1 = cvt_pk_bf16(hp[2], hp[3]);
        uint32_t hw2 = cvt_pk_bf16(hp[4], hp[5]);
        uint32_t hw3 = cvt_pk_bf16(hp[6], hp[7]);
        uint32_t ww  = cvt_pk_bf16(win, 0.f);

        // cross-half exchange: lane <-> lane^32
        uint32_t wsw = (uint32_t)__shfl_xor((int)ww , 32);
        uint32_t h0s = (uint32_t)__shfl_xor((int)hw0, 32);
        uint32_t h1s = (uint32_t)__shfl_xor((int)hw1, 32);
        uint32_t h2s = (uint32_t)__shfl_xor((int)hw2, 32);
        uint32_t h3s = (uint32_t)__shfl_xor((int)hw3, 32);

        // nsub 0: cols j = jt*64 + (0..31); nsub 1: cols j = jt*64+32+(0..31)
        short8 B0 = frag_of(lg2 == 0 ? hw0 : wsw,
                            lg2 == 0 ? hw1 : 0u,
                            lg2 == 0 ? hw2 : 0u,
                            lg2 == 0 ? hw3 : 0u);
        short8 B1 = frag_of(lg2 == 0 ? h0s : ww,
                            lg2 == 0 ? h1s : 0u,
                            lg2 == 0 ? h2s : 0u,
                            lg2 == 0 ? h3s : 0u);

        #pragma unroll
        for (int ns = 0; ns < 2; ++ns) {
            short8 Bf = ns ? B1 : B0;
            int rowb = (jt * 64 + ns * 32 + jj0) * 16;
            #pragma unroll
            for (int m = 0; m < 2; ++m) {
                f32x16 C = __builtin_amdgcn_mfma_f32_32x32x16_bf16(
                    Af[m], Bf, z16, 0, 0, 0);
                #pragma unroll
                for (int q = 0; q < 4; ++q) {
                    uint2 u = fh[rowb + m * 8 + ccq[q]];
                    float f0 = bf16lo_to_f(u.x);
                    float f1 = bf16hi_to_f(u.x);
                    float f2 = bf16lo_to_f(u.y);
                    float f3 = bf16hi_to_f(u.y);
                    float x0 = fmaxf(C[4 * q + 0], 0.f);
                    float x1 = fmaxf(C[4 * q + 1], 0.f);
                    float x2 = fmaxf(C[4 * q + 2], 0.f);
                    float x3 = fmaxf(C[4 * q + 3], 0.f);
                    acc[m][4 * q + 0] = fmaf(x0, f0, acc[m][4 * q + 0]);
                    acc[m][4 * q + 1] = fmaf(x1, f1, acc[m][4 * q + 1]);
                    acc[m][4 * q + 2] = fmaf(x2, f2, acc[m][4 * q + 2]);
                    acc[m][4 * q + 3] = fmaf(x3, f3, acc[m][4 * q + 3]);
                }
            }
        }
    }

    // reduce over the 32 j-columns held across l31 (within each 32-half)
    #pragma unroll
    for (int m = 0; m < 2; ++m)
        #pragma unroll
        for (int r = 0; r < 16; ++r) {
            float v = acc[m][r];
            v += __shfl_xor(v, 1);
            v += __shfl_xor(v, 2);
            v += __shfl_xor(v, 4);
            v += __shfl_xor(v, 8);
            v += __shfl_xor(v, 16);
            acc[m][r] = v;
        }

    if (l31 == 0) {   // lanes 0 and 32 hold disjoint channel sets
        #pragma unroll
        for (int m = 0; m < 2; ++m)
            #pragma unroll
            for (int r = 0; r < 16; ++r)
                red[wv][m * 32 + (ccq[r >> 2] << 2) + (r & 3)] = acc[m][r];
    }
    __syncthreads();
    if (tid < H_DIM) {
        out[i * H_DIM + tid] = red[0][tid] + red[1][tid] + red[2][tid] + red[3][tid];
    }
}

// ---------------------------------------------------------------------------
// k_back: fused output MLP + GN2 per-block partials (no atomics)
// ---------------------------------------------------------------------------
__global__ __launch_bounds__(256) void k_back(
    const float* __restrict__ fin, const float* __restrict__ W1,
    const float* __restrict__ b1, const float* __restrict__ W2,
    const float* __restrict__ b2, float* __restrict__ out,
    float* __restrict__ part)
{
    __shared__ float t1s[4][O_DIM];
    __shared__ float sred[16], qred[16];
    int tid = threadIdx.x;
    int pl = tid >> 6, o = tid & 63;
    int n = blockIdx.x * 4 + pl;
    const float* fr = fin + n * H_DIM;
    float s = b1[o];
    #pragma unroll
    for (int k = 0; k < H_DIM; ++k) s = fmaf(fr[k], W1[o * H_DIM + k], s);
    s = s > 0.f ? s : 0.2f * s;
    t1s[pl][o] = s;
    __syncthreads();
    float t = b2[o];
    #pragma unroll
    for (int k = 0; k < O_DIM; ++k) t = fmaf(t1s[pl][k], W2[o * O_DIM + k], t);
    t = t > 0.f ? t : 0.2f * t;
    out[n * O_DIM + o] = t;

    float ss = t, qq = t * t;
    #pragma unroll
    for (int off = 8; off >= 1; off >>= 1) {
        ss += __shfl_xor(ss, off);
        qq += __shfl_xor(qq, off);
    }
    int grp = pl * 4 + (o >> 4);
    if ((o & 15) == 0) { sred[grp] = ss; qred[grp] = qq; }
    __syncthreads();
    if (tid < 4) {
        float S = sred[tid] + sred[4 + tid] + sred[8 + tid] + sred[12 + tid];
        float Q = qred[tid] + qred[4 + tid] + qred[8 + tid] + qred[12 + tid];
        part[blockIdx.x * 8 + tid]     = S;
        part[blockIdx.x * 8 + 4 + tid] = Q;
    }
}

// ---------------------------------------------------------------------------
// k_apply2: reduce GN2 partials + normalize f32 in-place on d_out
// ---------------------------------------------------------------------------
__global__ __launch_bounds__(256) void k_apply2(
    float* __restrict__ x, const float* __restrict__ part,
    const float* __restrict__ w, const float* __restrict__ b)
{
    __shared__ float s8[4][8];
    int tid = threadIdx.x;
    const f32x4* p4 = (const f32x4*)part;
    f32x4 sa = p4[tid * 4 + 0], qa = p4[tid * 4 + 1];
    f32x4 sb = p4[tid * 4 + 2], qb = p4[tid * 4 + 3];
    float sv0 = sa.x + sb.x, sv1 = sa.y + sb.y, sv2 = sa.z + sb.z, sv3 = sa.w + sb.w;
    float qv0 = qa.x + qb.x, qv1 = qa.y + qb.y, qv2 = qa.z + qb.z, qv3 = qa.w + qb.w;
    #pragma unroll
    for (int off = 1; off <= 32; off <<= 1) {
        sv0 += __shfl_xor(sv0, off); sv1 += __shfl_xor(sv1, off);
        sv2 += __shfl_xor(sv2, off); sv3 += __shfl_xor(sv3, off);
        qv0 += __shfl_xor(qv0, off); qv1 += __shfl_xor(qv1, off);
        qv2 += __shfl_xor(qv2, off); qv3 += __shfl_xor(qv3, off);
    }
    int lane = tid & 63, wvv = tid >> 6;
    if (lane == 0) {
        s8[wvv][0] = sv0; s8[wvv][1] = sv1; s8[wvv][2] = sv2; s8[wvv][3] = sv3;
        s8[wvv][4] = qv0; s8[wvv][5] = qv1; s8[wvv][6] = qv2; s8[wvv][7] = qv3;
    }
    __syncthreads();
    int idx2 = blockIdx.x * 256 + tid;
    int e = idx2 * 2;
    int ch = e & 63;
    int g = ch >> 4;
    float S = s8[0][g] + s8[1][g] + s8[2][g] + s8[3][g];
    float Q = s8[0][4 + g] + s8[1][4 + g] + s8[2][4 + g] + s8[3][4 + g];
    float m = S / GN_TOT;
    float var = Q / GN_TOT - m * m;
    float r = rsqrtf(var + GN_EPS);
    float2 v = ((const float2*)x)[idx2];
    float v0 = (v.x - m) * r * w[ch]     + b[ch];
    float v1 = (v.y - m) * r * w[ch + 1] + b[ch + 1];
    ((float2*)x)[idx2] = make_float2(v0, v1);
}

// ---------------------------------------------------------------------------
extern "C" void kernel_launch(void* const* d_in, const int* in_sizes, int n_in,
                              void* d_out, int out_size, void* d_ws, size_t ws_size,
                              hipStream_t stream)
{
    const float* points   = (const float*)d_in[0];
    const float* nuv      = (const float*)d_in[1];
    const float* features = (const float*)d_in[2];
    const float* W_in1    = (const float*)d_in[3];
    const float* b_in1    = (const float*)d_in[4];
    const float* W_in2    = (const float*)d_in[5];
    const float* b_in2    = (const float*)d_in[6];
    const float* gn_in_w  = (const float*)d_in[7];
    const float* gn_in_b  = (const float*)d_in[8];
    const float* cw1      = (const float*)d_in[9];
    const float* cb1      = (const float*)d_in[10];
    const float* cw2      = (const float*)d_in[11];
    const float* cb2      = (const float*)d_in[12];
    const float* W_out1   = (const float*)d_in[13];
    const float* b_out1   = (const float*)d_in[14];
    const float* W_out2   = (const float*)d_in[15];
    const float* b_out2   = (const float*)d_in[16];
    const float* gn_out_w = (const float*)d_in[17];
    const float* gn_out_b = (const float*)d_in[18];

    float*    bufA  = (float*)d_ws;                  // N*64 f32
    float*    pjp   = bufA + N_PTS * H_DIM;          // N*8 f32
    uint32_t* fbh   = (uint32_t*)(pjp + N_PTS * 8);  // N*32 dwords (bf16 pairs)
    float*    part1 = (float*)(fbh + N_PTS * 32);    // 512*8 f32
    float*    part2 = part1 + 512 * 8;               // 512*8 f32
    float*    outp  = (float*)d_out;

    k_front    <<<N_PTS / 4, 256, 0, stream>>>(points, nuv, features,
                                               W_in1, b_in1, W_in2, b_in2,
                                               bufA, pjp, part1);
    k_apply1   <<<N_PTS * H_DIM / 512, 256, 0, stream>>>(bufA, part1,
                                               gn_in_w, gn_in_b, fbh);
    k_conv_mfma<<<N_PTS, 256, 0, stream>>>(pjp, nuv, cw1, cb1, cw2, cb2,
                                               fbh, bufA);
    k_back     <<<N_PTS / 4, 256, 0, stream>>>(bufA, W_out1, b_out1,
                                               W_out2, b_out2, outp, part2);
    k_apply2   <<<N_PTS * O_DIM / 512, 256, 0, stream>>>(outp, part2,
                                               gn_out_w, gn_out_b);
}